// Round 1
// baseline (3680.361 us; speedup 1.0000x reference)
//
#include <hip/hip_runtime.h>
#include <math.h>

namespace {
constexpr int Bn = 8, Tn = 4096, Hn = 4, HVn = 8, Kn = 128, Vn = 128;
constexpr int SK = 8;            // k-splits per column (per wave)
constexpr int EPL = Kn / SK;     // 16 state elements per lane
constexpr int BV = 8;            // columns per wave
constexpr int DEPTH = 4;         // register prefetch depth (Tn % DEPTH == 0)
constexpr float SCALE = 0.088388347648318447f; // 128^-0.5
}

__global__ __launch_bounds__(64, 1) void gdn_recurrent(
    const float* __restrict__ A_log, const float* __restrict__ a_in,
    const float* __restrict__ dt_bias, const float* __restrict__ q_in,
    const float* __restrict__ k_in, const float* __restrict__ v_in,
    const float* __restrict__ b_in, const float* __restrict__ h0_src,
    const int* __restrict__ h0_idx, float* __restrict__ out)
{
  const int blk = blockIdx.x;
  // XCD swizzle: the 16 blocks of one (b,hv) share blk%8 -> same XCD L2.
  const int g    = (blk & 7) + ((blk >> 7) << 3);  // (b,hv) group in [0,64)
  const int vblk = (blk >> 3) & 15;
  const int b  = g >> 3;
  const int hv = g & 7;
  const int h  = hv >> 1;          // GQA: rep = HV/H = 2
  const int lane = threadIdx.x;
  const int kk = lane >> 3;        // k-split id [0,8)
  const int vv = lane & 7;         // column within wave [0,8)
  const int vg = vblk * BV + vv;   // global V index
  const int k0 = kk * EPL;

  // ---- state: this lane's 16-row slice of column vg ----
  float hs[EPL];
  const int idx = h0_idx[b];
  if (idx >= 0) {
    const float* hp = h0_src + (((long)idx * HVn + hv) * Kn + k0) * Vn + vg;
#pragma unroll
    for (int j = 0; j < EPL; ++j) hs[j] = hp[(long)j * Vn];
  } else {
#pragma unroll
    for (int j = 0; j < EPL; ++j) hs[j] = 0.f;
  }

  const float negA = -expf(A_log[hv]);
  const float dtb  = dt_bias[hv];

  // ---- rotating register prefetch buffers ----
  float kb[DEPTH][EPL], qb[DEPTH][EPL];
  float vb[DEPTH], ab[DEPTH], bb[DEPTH];

  auto load_step = [&](int t, float* kd, float* qd, float& vd, float& ad, float& bd) {
    const int tc = t < Tn ? t : Tn - 1;   // clamp; extra loads are harmless
    const float* kp = k_in + (((long)b * Tn + tc) * Hn + h) * Kn + k0;
    const float* qp = q_in + (((long)b * Tn + tc) * Hn + h) * Kn + k0;
#pragma unroll
    for (int j = 0; j < EPL; j += 4) {
      const float4 kv = *reinterpret_cast<const float4*>(kp + j);
      kd[j] = kv.x; kd[j+1] = kv.y; kd[j+2] = kv.z; kd[j+3] = kv.w;
      const float4 qv = *reinterpret_cast<const float4*>(qp + j);
      qd[j] = qv.x; qd[j+1] = qv.y; qd[j+2] = qv.z; qd[j+3] = qv.w;
    }
    vd = v_in[(((long)b * Tn + tc) * HVn + hv) * Vn + vg];
    const long sidx = ((long)b * Tn + tc) * HVn + hv;
    ad = a_in[sidx];
    bd = b_in[sidx];
  };

#pragma unroll
  for (int d = 0; d < DEPTH; ++d)
    load_step(d, kb[d], qb[d], vb[d], ab[d], bb[d]);

  for (int t0i = 0; t0i < Tn; t0i += DEPTH) {
#pragma unroll
    for (int ph = 0; ph < DEPTH; ++ph) {
      const int t = t0i + ph;

      // per-step scalars (wave-uniform; computed redundantly per lane)
      const float x    = ab[ph] + dtb;
      const float sp   = (x <= 20.0f) ? log1pf(expf(x)) : x;   // softplus
      const float eg   = expf(negA * sp);                       // exp(g_t)
      const float beta = 1.0f / (1.0f + expf(-bb[ph]));         // sigmoid

      // ---- pass 1: dot(h_old, k_raw) and sum(k_raw^2) over this slice ----
      float d0=0.f,d1=0.f,d2=0.f,d3=0.f, s0=0.f,s1=0.f,s2=0.f,s3=0.f;
#pragma unroll
      for (int j = 0; j < EPL; j += 4) {
        d0 = fmaf(hs[j],   kb[ph][j],   d0); s0 = fmaf(kb[ph][j],   kb[ph][j],   s0);
        d1 = fmaf(hs[j+1], kb[ph][j+1], d1); s1 = fmaf(kb[ph][j+1], kb[ph][j+1], s1);
        d2 = fmaf(hs[j+2], kb[ph][j+2], d2); s2 = fmaf(kb[ph][j+2], kb[ph][j+2], s2);
        d3 = fmaf(hs[j+3], kb[ph][j+3], d3); s3 = fmaf(kb[ph][j+3], kb[ph][j+3], s3);
      }
      float dot = (d0 + d1) + (d2 + d3);
      float ksq = (s0 + s1) + (s2 + s3);
#pragma unroll
      for (int m = 8; m <= 32; m <<= 1) {
        dot += __shfl_xor(dot, m);
        ksq += __shfl_xor(ksq, m);
      }
      // fold l2norm(k) into the scalar: kn = k * rk
      const float rk = rsqrtf(ksq + 1e-6f);
      const float u  = (vb[ph] - eg * dot * rk) * beta * rk;

      // ---- pass 2: state update + dot(h_new, q_raw) + sum(q^2) ----
      float o0=0.f,o1=0.f,o2=0.f,o3=0.f, w0=0.f,w1=0.f,w2=0.f,w3=0.f;
#pragma unroll
      for (int j = 0; j < EPL; j += 4) {
        hs[j]   = fmaf(hs[j],   eg, kb[ph][j]   * u);
        hs[j+1] = fmaf(hs[j+1], eg, kb[ph][j+1] * u);
        hs[j+2] = fmaf(hs[j+2], eg, kb[ph][j+2] * u);
        hs[j+3] = fmaf(hs[j+3], eg, kb[ph][j+3] * u);
        o0 = fmaf(hs[j],   qb[ph][j],   o0); w0 = fmaf(qb[ph][j],   qb[ph][j],   w0);
        o1 = fmaf(hs[j+1], qb[ph][j+1], o1); w1 = fmaf(qb[ph][j+1], qb[ph][j+1], w1);
        o2 = fmaf(hs[j+2], qb[ph][j+2], o2); w2 = fmaf(qb[ph][j+2], qb[ph][j+2], w2);
        o3 = fmaf(hs[j+3], qb[ph][j+3], o3); w3 = fmaf(qb[ph][j+3], qb[ph][j+3], w3);
      }
      float od  = (o0 + o1) + (o2 + o3);
      float qsq = (w0 + w1) + (w2 + w3);
#pragma unroll
      for (int m = 8; m <= 32; m <<= 1) {
        od  += __shfl_xor(od, m);
        qsq += __shfl_xor(qsq, m);
      }
      const float oval = od * rsqrtf(qsq + 1e-6f) * SCALE;
      if (kk == 0)
        out[(((long)b * Tn + t) * HVn + hv) * Vn + vg] = oval;

      // ---- prefetch step t+DEPTH into the slot just consumed ----
      load_step(t + DEPTH, kb[ph], qb[ph], vb[ph], ab[ph], bb[ph]);
    }
  }
}

extern "C" void kernel_launch(void* const* d_in, const int* in_sizes, int n_in,
                              void* d_out, int out_size, void* d_ws, size_t ws_size,
                              hipStream_t stream) {
  const float* A_log = (const float*)d_in[0];
  const float* a_in  = (const float*)d_in[1];
  const float* dtb   = (const float*)d_in[2];
  const float* q_in  = (const float*)d_in[3];
  const float* k_in  = (const float*)d_in[4];
  const float* v_in  = (const float*)d_in[5];
  const float* b_in  = (const float*)d_in[6];
  const float* h0    = (const float*)d_in[7];
  const int*   idx   = (const int*)d_in[8];
  float* out = (float*)d_out;

  dim3 grid(Bn * HVn * (Vn / BV));  // 1024 blocks = 1024 waves
  dim3 block(64);
  gdn_recurrent<<<grid, block, 0, stream>>>(A_log, a_in, dtb, q_in, k_in, v_in,
                                            b_in, h0, idx, out);
}

// Round 2
// 2734.942 us; speedup vs baseline: 1.3457x; 1.3457x over previous
//
#include <hip/hip_runtime.h>
#include <math.h>

namespace {
constexpr int Bn = 8, Tn = 4096, Hn = 4, HVn = 8, Kn = 128, Vn = 128;
constexpr int DEPTH = 4;                        // register prefetch depth
constexpr float SCALE = 0.088388347648318447f;  // 128^-0.5
}

// ---------------- pre-pass: per-(b,t) scalars ----------------
// S[(b*T+t)*HV + hv] = { eg, beta*rk, eg*rk, rq*SCALE }
__global__ __launch_bounds__(64) void gdn_prepass(
    const float* __restrict__ A_log, const float* __restrict__ a_in,
    const float* __restrict__ dt_bias, const float* __restrict__ q_in,
    const float* __restrict__ k_in, const float* __restrict__ b_in,
    float4* __restrict__ S)
{
  const int bt = blockIdx.x;          // b*Tn + t
  const int lane = threadIdx.x;
  const int h  = lane >> 4;           // 16 lanes per head
  const int j0 = (lane & 15) * 8;

  const float* kp = k_in + ((long)bt * Hn + h) * Kn + j0;
  const float* qp = q_in + ((long)bt * Hn + h) * Kn + j0;
  const float4 ka = *(const float4*)kp;
  const float4 kb = *(const float4*)(kp + 4);
  const float4 qa = *(const float4*)qp;
  const float4 qb = *(const float4*)(qp + 4);

  float ks = ka.x*ka.x + ka.y*ka.y + ka.z*ka.z + ka.w*ka.w
           + kb.x*kb.x + kb.y*kb.y + kb.z*kb.z + kb.w*kb.w;
  float qs = qa.x*qa.x + qa.y*qa.y + qa.z*qa.z + qa.w*qa.w
           + qb.x*qb.x + qb.y*qb.y + qb.z*qb.z + qb.w*qb.w;
#pragma unroll
  for (int m = 1; m <= 8; m <<= 1) {
    ks += __shfl_xor(ks, m);
    qs += __shfl_xor(qs, m);
  }
  const float rk = rsqrtf(ks + 1e-6f);
  const float rq = rsqrtf(qs + 1e-6f);

  // broadcast rk/rq of head (lane&7)>>1 to the low 8 lanes
  const int src = (((lane & 7) >> 1) << 4);
  const float rkh = __shfl(rk, src);
  const float rqh = __shfl(rq, src);

  if (lane < 8) {
    const int hv = lane;
    const long sidx = (long)bt * HVn + hv;
    const float x  = a_in[sidx] + dt_bias[hv];
    const float sp = (x <= 20.0f) ? log1pf(expf(x)) : x;   // softplus
    const float eg = expf(-expf(A_log[hv]) * sp);
    const float beta = 1.0f / (1.0f + expf(-b_in[sidx]));
    S[sidx] = make_float4(eg, beta * rkh, eg * rkh, rqh * SCALE);
  }
}

// ---------------- recurrent scan ----------------
__device__ __forceinline__ void dot4(const float4 h, const float4 k,
                                     float& a0, float& a1, float& a2, float& a3) {
  a0 = fmaf(h.x, k.x, a0); a1 = fmaf(h.y, k.y, a1);
  a2 = fmaf(h.z, k.z, a2); a3 = fmaf(h.w, k.w, a3);
}
__device__ __forceinline__ void scale4(float4& h, const float c) {
  h.x *= c; h.y *= c; h.z *= c; h.w *= c;
}
__device__ __forceinline__ void axpy4(float4& h, const float4 k, const float u) {
  h.x = fmaf(k.x, u, h.x); h.y = fmaf(k.y, u, h.y);
  h.z = fmaf(k.z, u, h.z); h.w = fmaf(k.w, u, h.w);
}

__device__ __forceinline__ void gdn_step(
    const int t, const int lane,
    float4& h0, float4& h1, float4& h2, float4& h3,
    const float4 k0, const float4 k1, const float4 k2, const float4 k3,
    const float4 q0, const float4 q1, const float4 q2, const float4 q3,
    const float vval, const float4 s4, float* __restrict__ obase)
{
  const float c1 = s4.x, c2 = s4.y, c3 = s4.z, c4 = s4.w;

  // pass 1: dot(h_old, k_raw) over this lane's 16-row slice
  float a0 = 0.f, a1 = 0.f, a2 = 0.f, a3 = 0.f;
  dot4(h0, k0, a0, a1, a2, a3);
  dot4(h1, k1, a0, a1, a2, a3);
  dot4(h2, k2, a0, a1, a2, a3);
  dot4(h3, k3, a0, a1, a2, a3);
  float dot = (a0 + a1) + (a2 + a3);
  // decay is independent of the reduction -> overlaps shuffle latency
  scale4(h0, c1); scale4(h1, c1); scale4(h2, c1); scale4(h3, c1);
  dot += __shfl_xor(dot, 8);
  dot += __shfl_xor(dot, 16);
  dot += __shfl_xor(dot, 32);

  const float u = (vval - c3 * dot) * c2;   // (v - eg*rk*dot) * beta*rk

  // pass 2: h += k*u ; od = dot(h_new, q_raw)
  axpy4(h0, k0, u); axpy4(h1, k1, u); axpy4(h2, k2, u); axpy4(h3, k3, u);
  float o0 = 0.f, o1 = 0.f, o2 = 0.f, o3 = 0.f;
  dot4(h0, q0, o0, o1, o2, o3);
  dot4(h1, q1, o0, o1, o2, o3);
  dot4(h2, q2, o0, o1, o2, o3);
  dot4(h3, q3, o0, o1, o2, o3);
  float od = (o0 + o1) + (o2 + o3);
  od += __shfl_xor(od, 8);
  od += __shfl_xor(od, 16);
  od += __shfl_xor(od, 32);

  if (lane < 8)                              // kk==0 lanes: 8 contiguous floats
    obase[(long)t * (HVn * Vn)] = od * c4;   // od * rq * SCALE
}

__global__ __launch_bounds__(64, 1) void gdn_recurrent(
    const float* __restrict__ q_in, const float* __restrict__ k_in,
    const float* __restrict__ v_in, const float4* __restrict__ S,
    const float* __restrict__ h0_src, const int* __restrict__ h0_idx,
    float* __restrict__ out)
{
  const int blk = blockIdx.x;
  const int g    = (blk & 7) + ((blk >> 7) << 3);  // (b,hv) in [0,64), XCD-swizzled
  const int vblk = (blk >> 3) & 15;
  const int b  = g >> 3;
  const int hv = g & 7;
  const int h  = hv >> 1;          // GQA rep=2
  const int lane = threadIdx.x;
  const int kk = lane >> 3;        // k-split [0,8), 16 rows each
  const int vv = lane & 7;
  const int vg = vblk * 8 + vv;
  const int k0 = kk * 16;

  const float* kbase = k_in + (((long)b * Tn) * Hn + h) * Kn + k0;
  const float* qbase = q_in + (((long)b * Tn) * Hn + h) * Kn + k0;
  const float* vbase = v_in + (((long)b * Tn) * HVn + hv) * Vn + vg;
  const float4* sbase = S + (long)b * Tn * HVn + hv;
  float* obase = out + (((long)b * Tn) * HVn + hv) * Vn + vg;

  // rotating 4-deep register prefetch, explicit float4 slots
  float4 kb[DEPTH][4], qb[DEPTH][4], sb[DEPTH];
  float  vb[DEPTH];

#define LOAD_SLOT(p, tt)                                                   \
  {                                                                        \
    const int tc = (tt) < Tn ? (tt) : Tn - 1;                              \
    const float4* kp = (const float4*)(kbase + (long)tc * (Hn * Kn));      \
    const float4* qp = (const float4*)(qbase + (long)tc * (Hn * Kn));      \
    kb[p][0] = kp[0]; kb[p][1] = kp[1]; kb[p][2] = kp[2]; kb[p][3] = kp[3];\
    qb[p][0] = qp[0]; qb[p][1] = qp[1]; qb[p][2] = qp[2]; qb[p][3] = qp[3];\
    vb[p] = vbase[(long)tc * (HVn * Vn)];                                  \
    sb[p] = sbase[(long)tc * HVn];                                         \
  }

  LOAD_SLOT(0, 0) LOAD_SLOT(1, 1) LOAD_SLOT(2, 2) LOAD_SLOT(3, 3)

  // state: 16 rows x 1 column per lane (startup scalar loads overlap prefetch)
  float4 hs0, hs1, hs2, hs3;
  const int idx = h0_idx[b];
  if (idx >= 0) {
    const float* hp = h0_src + (((long)idx * HVn + hv) * Kn + k0) * Vn + vg;
    hs0 = make_float4(hp[0*Vn],  hp[1*Vn],  hp[2*Vn],  hp[3*Vn]);
    hs1 = make_float4(hp[4*Vn],  hp[5*Vn],  hp[6*Vn],  hp[7*Vn]);
    hs2 = make_float4(hp[8*Vn],  hp[9*Vn],  hp[10*Vn], hp[11*Vn]);
    hs3 = make_float4(hp[12*Vn], hp[13*Vn], hp[14*Vn], hp[15*Vn]);
  } else {
    hs0 = hs1 = hs2 = hs3 = make_float4(0.f, 0.f, 0.f, 0.f);
  }

  for (int t0 = 0; t0 < Tn; t0 += DEPTH) {
#pragma unroll
    for (int p = 0; p < DEPTH; ++p) {
      const int t = t0 + p;
      gdn_step(t, lane, hs0, hs1, hs2, hs3,
               kb[p][0], kb[p][1], kb[p][2], kb[p][3],
               qb[p][0], qb[p][1], qb[p][2], qb[p][3],
               vb[p], sb[p], obase);
      LOAD_SLOT(p, t + DEPTH)   // refill the slot just consumed
    }
  }
#undef LOAD_SLOT
}

extern "C" void kernel_launch(void* const* d_in, const int* in_sizes, int n_in,
                              void* d_out, int out_size, void* d_ws, size_t ws_size,
                              hipStream_t stream) {
  const float* A_log = (const float*)d_in[0];
  const float* a_in  = (const float*)d_in[1];
  const float* dtb   = (const float*)d_in[2];
  const float* q_in  = (const float*)d_in[3];
  const float* k_in  = (const float*)d_in[4];
  const float* v_in  = (const float*)d_in[5];
  const float* b_in  = (const float*)d_in[6];
  const float* h0    = (const float*)d_in[7];
  const int*   idx   = (const int*)d_in[8];
  float* out = (float*)d_out;
  float4* S  = (float4*)d_ws;     // B*T*HV float4 = 4 MB

  gdn_prepass<<<dim3(Bn * Tn), dim3(64), 0, stream>>>(A_log, a_in, dtb,
                                                      q_in, k_in, b_in, S);
  gdn_recurrent<<<dim3(1024), dim3(64), 0, stream>>>(q_in, k_in, v_in, S,
                                                     h0, idx, out);
}

// Round 3
// 2369.735 us; speedup vs baseline: 1.5531x; 1.1541x over previous
//
#include <hip/hip_runtime.h>
#include <math.h>

namespace {
constexpr int Bn = 8, Tn = 4096, Hn = 4, HVn = 8, Kn = 128, Vn = 128;
constexpr int DEPTH = 4;                        // register prefetch depth
constexpr float SCALE = 0.088388347648318447f;  // 128^-0.5
}

// ---------------- pre-pass: per-(b,t) scalars ----------------
// S[(b*T+t)*HV + hv] = { eg, beta*rk, eg*rk, rq*SCALE }
__global__ __launch_bounds__(64) void gdn_prepass(
    const float* __restrict__ A_log, const float* __restrict__ a_in,
    const float* __restrict__ dt_bias, const float* __restrict__ q_in,
    const float* __restrict__ k_in, const float* __restrict__ b_in,
    float4* __restrict__ S)
{
  const int bt = blockIdx.x;          // b*Tn + t
  const int lane = threadIdx.x;
  const int h  = lane >> 4;           // 16 lanes per head
  const int j0 = (lane & 15) * 8;

  const float* kp = k_in + ((long)bt * Hn + h) * Kn + j0;
  const float* qp = q_in + ((long)bt * Hn + h) * Kn + j0;
  const float4 ka = *(const float4*)kp;
  const float4 kb = *(const float4*)(kp + 4);
  const float4 qa = *(const float4*)qp;
  const float4 qb = *(const float4*)(qp + 4);

  float ks = ka.x*ka.x + ka.y*ka.y + ka.z*ka.z + ka.w*ka.w
           + kb.x*kb.x + kb.y*kb.y + kb.z*kb.z + kb.w*kb.w;
  float qs = qa.x*qa.x + qa.y*qa.y + qa.z*qa.z + qa.w*qa.w
           + qb.x*qb.x + qb.y*qb.y + qb.z*qb.z + qb.w*qb.w;
#pragma unroll
  for (int m = 1; m <= 8; m <<= 1) {
    ks += __shfl_xor(ks, m);
    qs += __shfl_xor(qs, m);
  }
  const float rk = rsqrtf(ks + 1e-6f);
  const float rq = rsqrtf(qs + 1e-6f);

  // broadcast rk/rq of head (lane&7)>>1 to the low 8 lanes
  const int src = (((lane & 7) >> 1) << 4);
  const float rkh = __shfl(rk, src);
  const float rqh = __shfl(rq, src);

  if (lane < 8) {
    const int hv = lane;
    const long sidx = (long)bt * HVn + hv;
    const float x  = a_in[sidx] + dt_bias[hv];
    const float sp = (x <= 20.0f) ? log1pf(expf(x)) : x;   // softplus
    const float eg = expf(-expf(A_log[hv]) * sp);
    const float beta = 1.0f / (1.0f + expf(-b_in[sidx]));
    S[sidx] = make_float4(eg, beta * rkh, eg * rkh, rqh * SCALE);
  }
}

// ---------------- recurrent scan ----------------
__device__ __forceinline__ void dot3_4(const float4 h, const float4 k, const float4 q,
                                       float& d1a, float& d1b,
                                       float& d2a, float& d2b,
                                       float& d3a, float& d3b) {
  // three dots share h/k/q registers; two partial accumulators each
  d1a = fmaf(h.x, k.x, d1a); d1b = fmaf(h.y, k.y, d1b);
  d1a = fmaf(h.z, k.z, d1a); d1b = fmaf(h.w, k.w, d1b);
  d2a = fmaf(h.x, q.x, d2a); d2b = fmaf(h.y, q.y, d2b);
  d2a = fmaf(h.z, q.z, d2a); d2b = fmaf(h.w, q.w, d2b);
  d3a = fmaf(k.x, q.x, d3a); d3b = fmaf(k.y, q.y, d3b);
  d3a = fmaf(k.z, q.z, d3a); d3b = fmaf(k.w, q.w, d3b);
}
__device__ __forceinline__ void upd4(float4& h, const float4 k,
                                     const float c1, const float up) {
  h.x = fmaf(k.x, up, h.x * c1); h.y = fmaf(k.y, up, h.y * c1);
  h.z = fmaf(k.z, up, h.z * c1); h.w = fmaf(k.w, up, h.w * c1);
}

__global__ __launch_bounds__(64, 1) void gdn_recurrent(
    const float* __restrict__ q_in, const float* __restrict__ k_in,
    const float* __restrict__ v_in, const float4* __restrict__ S,
    const float* __restrict__ h0_src, const int* __restrict__ h0_idx,
    float* __restrict__ out)
{
  const int blk = blockIdx.x;
  const int g    = (blk & 7) + ((blk >> 7) << 3);  // (b,hv) in [0,64), XCD-swizzled
  const int vblk = (blk >> 3) & 15;
  const int b  = g >> 3;
  const int hv = g & 7;
  const int h  = hv >> 1;          // GQA rep=2
  const int lane = threadIdx.x;
  const int kk = lane >> 3;        // k-split [0,8), 16 rows each
  const int vv = lane & 7;
  const int vg = vblk * 8 + vv;
  const int k0 = kk * 16;

  const float* kbase = k_in + (((long)b * Tn) * Hn + h) * Kn + k0;
  const float* qbase = q_in + (((long)b * Tn) * Hn + h) * Kn + k0;
  const float* vbase = v_in + (((long)b * Tn) * HVn + hv) * Vn + vg;
  const float4* sbase = S + (long)b * Tn * HVn + hv;
  float* obase = out + (((long)b * Tn) * HVn + hv) * Vn + vg;

  // rotating 4-deep register prefetch
  float4 kb[DEPTH][4], qb[DEPTH][4], sb[DEPTH];
  float  vb[DEPTH];

#define LOAD_SLOT(p, tt)                                                   \
  {                                                                        \
    const int tc = (tt) < Tn ? (tt) : Tn - 1;                              \
    const float4* kp = (const float4*)(kbase + (long)tc * (Hn * Kn));      \
    const float4* qp = (const float4*)(qbase + (long)tc * (Hn * Kn));      \
    kb[p][0] = kp[0]; kb[p][1] = kp[1]; kb[p][2] = kp[2]; kb[p][3] = kp[3];\
    qb[p][0] = qp[0]; qb[p][1] = qp[1]; qb[p][2] = qp[2]; qb[p][3] = qp[3];\
    vb[p] = vbase[(long)tc * (HVn * Vn)];                                  \
    sb[p] = sbase[(long)tc * HVn];                                         \
  }

  LOAD_SLOT(0, 0) LOAD_SLOT(1, 1) LOAD_SLOT(2, 2) LOAD_SLOT(3, 3)

  // state: 16 rows x 1 column per lane
  float4 hs0, hs1, hs2, hs3;
  const int idx = h0_idx[b];
  if (idx >= 0) {
    const float* hp = h0_src + (((long)idx * HVn + hv) * Kn + k0) * Vn + vg;
    hs0 = make_float4(hp[0*Vn],  hp[1*Vn],  hp[2*Vn],  hp[3*Vn]);
    hs1 = make_float4(hp[4*Vn],  hp[5*Vn],  hp[6*Vn],  hp[7*Vn]);
    hs2 = make_float4(hp[8*Vn],  hp[9*Vn],  hp[10*Vn], hp[11*Vn]);
    hs3 = make_float4(hp[12*Vn], hp[13*Vn], hp[14*Vn], hp[15*Vn]);
  } else {
    hs0 = hs1 = hs2 = hs3 = make_float4(0.f, 0.f, 0.f, 0.f);
  }

  for (int t0 = 0; t0 < Tn; t0 += DEPTH) {
#pragma unroll
    for (int p = 0; p < DEPTH; ++p) {
      const int t = t0 + p;

      // -- rename slot p into temps (SSA; frees slot regs for the prefetch) --
      const float4 tk0 = kb[p][0], tk1 = kb[p][1], tk2 = kb[p][2], tk3 = kb[p][3];
      const float4 tq0 = qb[p][0], tq1 = qb[p][1], tq2 = qb[p][2], tq3 = qb[p][3];
      const float  tv  = vb[p];
      const float4 ts  = sb[p];
      const float c1 = ts.x, c2 = ts.y, c3 = ts.z, c4 = ts.w;

      // -- three dots from h_prev, k_raw, q_raw simultaneously --
      float d1a = 0.f, d1b = 0.f, d2a = 0.f, d2b = 0.f, d3a = 0.f, d3b = 0.f;
      dot3_4(hs0, tk0, tq0, d1a, d1b, d2a, d2b, d3a, d3b);
      dot3_4(hs1, tk1, tq1, d1a, d1b, d2a, d2b, d3a, d3b);
      dot3_4(hs2, tk2, tq2, d1a, d1b, d2a, d2b, d3a, d3b);
      dot3_4(hs3, tk3, tq3, d1a, d1b, d2a, d2b, d3a, d3b);
      float d1 = d1a + d1b, d2 = d2a + d2b, d3 = d3a + d3b;

      // -- prefetch slot p for t+DEPTH; pin with a scheduler barrier so the
      //    loads can neither sink to their use nor cross later steps --
      LOAD_SLOT(p, t + DEPTH)
      __builtin_amdgcn_sched_barrier(0);

      // -- single reduction phase: 3 values, masks 8/16/32 (reduce over kk) --
#pragma unroll
      for (int m = 8; m <= 32; m <<= 1) {
        d1 += __shfl_xor(d1, m);
        d2 += __shfl_xor(d2, m);
        d3 += __shfl_xor(d3, m);
      }

      const float up = (tv - c3 * d1) * c2;        // rk * u
      const float o  = fmaf(c1, d2, up * d3) * c4; // (eg*d2 + u'*d3) * rq*scale

      upd4(hs0, tk0, c1, up); upd4(hs1, tk1, c1, up);
      upd4(hs2, tk2, c1, up); upd4(hs3, tk3, c1, up);

      if (lane < 8)                                 // kk==0 lanes, 8 contiguous
        obase[(long)t * (HVn * Vn)] = o;
    }
  }
#undef LOAD_SLOT
}

extern "C" void kernel_launch(void* const* d_in, const int* in_sizes, int n_in,
                              void* d_out, int out_size, void* d_ws, size_t ws_size,
                              hipStream_t stream) {
  const float* A_log = (const float*)d_in[0];
  const float* a_in  = (const float*)d_in[1];
  const float* dtb   = (const float*)d_in[2];
  const float* q_in  = (const float*)d_in[3];
  const float* k_in  = (const float*)d_in[4];
  const float* v_in  = (const float*)d_in[5];
  const float* b_in  = (const float*)d_in[6];
  const float* h0    = (const float*)d_in[7];
  const int*   idx   = (const int*)d_in[8];
  float* out = (float*)d_out;
  float4* S  = (float4*)d_ws;     // B*T*HV float4 = 4 MB

  gdn_prepass<<<dim3(Bn * Tn), dim3(64), 0, stream>>>(A_log, a_in, dtb,
                                                      q_in, k_in, b_in, S);
  gdn_recurrent<<<dim3(1024), dim3(64), 0, stream>>>(q_in, k_in, v_in, S,
                                                     h0, idx, out);
}